// Round 14
// baseline (2975.802 us; speedup 1.0000x reference)
//
#include <hip/hip_runtime.h>
#include <hip/hip_bf16.h>
#include <cstddef>
#include <cstdint>

#define NB 2

#define NMAX512 32768
#define NMAX256 28672
#define NMAX128 20480
#define NMAX64  8192
#define NMAX32  2048

typedef __attribute__((ext_vector_type(8))) short bf8v;    // 8 bf16 = 4 VGPR
typedef __attribute__((ext_vector_type(4))) float f32x4;
typedef __attribute__((ext_vector_type(16))) float f32x16;

static __device__ __forceinline__ unsigned short f2bf(float x) {
  __hip_bfloat16 h = __float2bfloat16(x);
  return *reinterpret_cast<unsigned short*>(&h);
}
static __device__ __forceinline__ float bf2f(unsigned short u) {
  __hip_bfloat16 h;
  *reinterpret_cast<unsigned short*>(&h) = u;
  return __bfloat162float(h);
}

// ------------------------------------------------------------------ list build (res 512 from x, Cin=1)
__global__ __launch_bounds__(256) void build_l0_k(const float* __restrict__ x,
    int* __restrict__ list, int* __restrict__ im, float* __restrict__ f0,
    int* __restrict__ nact, int total, int nmax) {
  int i = blockIdx.x * 256 + threadIdx.x;
  bool act = false;
  float v = 0.f;
  if (i < total) { v = x[i]; act = (v != 0.f); }
  unsigned long long mb = __ballot(act);
  int lane = threadIdx.x & 63;
  int prefix = __popcll(mb & ((1ull << lane) - 1));
  int base = 0;
  if (lane == 0) base = atomicAdd(nact, __popcll(mb));
  base = __shfl(base, 0);
  if (i < total) {
    int idx = act ? (base + prefix) : -1;
    if (idx >= nmax) idx = -1;
    im[i] = idx;
    if (idx >= 0) {
      int b = i >> 18;
      int rem = i & 262143;
      list[idx] = (b << 20) | ((rem >> 9) << 10) | (rem & 511);
      f0[idx] = v;
    }
  }
}

// ------------------------------------------------------------------ pooled list from finer idxmap
__global__ __launch_bounds__(256) void build_pl_k(const int* __restrict__ imF,
    int* __restrict__ list, int* __restrict__ im, int* __restrict__ nact,
    int Hc, int nmax) {
  int total = NB * Hc * Hc;
  int i = blockIdx.x * 256 + threadIdx.x;
  bool act = false;
  int b = 0, y = 0, x = 0;
  int Hf = Hc * 2;
  if (i < total) {
    x = i % Hc; y = (i / Hc) % Hc; b = i / (Hc * Hc);
    const int* p = imF + ((size_t)b * Hf + 2 * y) * Hf + 2 * x;
    act = (p[0] >= 0) || (p[1] >= 0) || (p[Hf] >= 0) || (p[Hf + 1] >= 0);
  }
  unsigned long long mb = __ballot(act);
  int lane = threadIdx.x & 63;
  int prefix = __popcll(mb & ((1ull << lane) - 1));
  int base = 0;
  if (lane == 0) base = atomicAdd(nact, __popcll(mb));
  base = __shfl(base, 0);
  if (i < total) {
    int idx = act ? (base + prefix) : -1;
    if (idx >= nmax) idx = -1;
    im[i] = idx;
    if (idx >= 0) list[idx] = (b << 20) | (y << 10) | x;
  }
}

// ------------------------------------------------------------------ 9-neighbor index table
__global__ __launch_bounds__(256) void build_nbr_k(const int* __restrict__ list,
    const int* __restrict__ im, const int* __restrict__ nactp,
    int* __restrict__ nbr, int H, int nmax) {
  int i = blockIdx.x * 256 + threadIdx.x;
  if (i >= nactp[0]) return;
  int code = list[i];
  int b = code >> 20, y = (code >> 10) & 1023, x = code & 1023;
#pragma unroll
  for (int k = 0; k < 9; ++k) {
    int yy = y + k / 3 - 1, xx = x + k % 3 - 1;
    int v = -1;
    if (yy >= 0 && yy < H && xx >= 0 && xx < H)
      v = im[((size_t)b * H + yy) * H + xx];
    nbr[k * nmax + i] = v;
  }
}

// ------------------------------------------------------------------ weight transpose  [R][C] -> [C][R]   (L1-L4 fp32 path)
__global__ __launch_bounds__(256) void transpose_k(const float* __restrict__ in,
                                                   float* __restrict__ out,
                                                   int R, int C) {
  __shared__ float tile[32][33];
  int bx = blockIdx.x * 32;
  int by = blockIdx.y * 32;
  int tx = threadIdx.x % 32, ty0 = threadIdx.x / 32;
  for (int ty = ty0; ty < 32; ty += 8) {
    int r = by + ty, c = bx + tx;
    tile[ty][tx] = (r < R && c < C) ? in[(size_t)r * C + c] : 0.f;
  }
  __syncthreads();
  for (int ty = ty0; ty < 32; ty += 8) {
    int r = bx + ty, c = by + tx;
    if (r < C && c < R) out[(size_t)r * R + c] = tile[tx][ty];
  }
}

// ------------------------------------------------------------------ weight bf16x3 split  w[Cout][Cin][9] -> wx[p][k][oc][cin]
__global__ __launch_bounds__(256) void wprep_k(const float* __restrict__ w,
                                               unsigned short* __restrict__ wx,
                                               int Cout, int Cin) {
  int i = blockIdx.x * 256 + threadIdx.x;
  if (i >= Cout * Cin) return;
  int oc = i / Cin, ci = i - oc * Cin;
  const float* src = w + ((size_t)oc * Cin + ci) * 9;
  const size_t sk = (size_t)Cout * Cin;
#pragma unroll
  for (int k = 0; k < 9; ++k) {
    float x = src[k];
    unsigned short h = f2bf(x);
    float r1 = x - bf2f(h);
    unsigned short m = f2bf(r1);
    float r2 = r1 - bf2f(m);
    wx[(size_t)k * sk + i] = h;
    wx[(size_t)(9 + k) * sk + i] = m;
    wx[(size_t)(18 + k) * sk + i] = f2bf(r2);
  }
}

// ------------------------------------------------------------------ gather-GEMM fp32 (256 thr, 4x8; L1-L4 only)
template <int CC, int SITES, int OCB, int SPT, int OPT>
__global__ __launch_bounds__(256, 2) void gconv_k(
    const float* __restrict__ in, float* __restrict__ out,
    const float* __restrict__ wT, const float* __restrict__ bias,
    const int* __restrict__ nbr, const int* __restrict__ nactp,
    int Cin, int Cout, int Nmax, int cinCnt, int nocb) {
  constexpr int KSL = CC * 9;
  __shared__ int s_nbr[9][SITES];
  __shared__ float s_a[KSL][SITES];
  __shared__ float s_w[KSL][OCB];
  const int n = nactp[0];
  const int gid = blockIdx.x;
  const int xcd = gid & 7;
  const int pos = gid >> 3;
  const int ocbI = pos % nocb;
  const int sb = (pos / nocb) * 8 + xcd;
  const int base = sb * SITES;
  if (base >= n) return;
  const int ocb = ocbI * OCB;
  const int t = threadIdx.x;
  for (int s = t; s < 9 * SITES; s += 256) {
    int i = s % SITES, k = s / SITES;
    int gi = base + i;
    s_nbr[k][i] = (gi < n) ? nbr[k * Nmax + gi] : -1;
  }
  constexpr int OCG = OCB / OPT;
  const int oc0 = (t % OCG) * 4;
  const int si0 = (t / OCG) * SPT;
  float acc[SPT][OPT];
#pragma unroll
  for (int a = 0; a < SPT; ++a)
#pragma unroll
    for (int j = 0; j < OPT; ++j) acc[a][j] = 0.f;
  __syncthreads();
  const int nch = cinCnt / CC;
  for (int ch = 0; ch < nch; ++ch) {
    const int c0 = ch * CC;
    const float* wrow = wT + ((size_t)c0 * 9) * Cout + ocb;
    for (int s = t; s < KSL * (OCB / 4); s += 256) {
      int j4 = s % (OCB / 4), r = s / (OCB / 4);
      *(float4*)&s_w[r][j4 * 4] = *(const float4*)(wrow + (size_t)r * Cout + j4 * 4);
    }
    if constexpr (CC == 1) {
      for (int s = t; s < 9 * SITES; s += 256) {
        int i = s % SITES, k = s / SITES;
        int row = s_nbr[k][i];
        s_a[k][i] = (row >= 0) ? in[row] : 0.f;
      }
    } else {
      constexpr int H4 = CC / 4;
      for (int s = t; s < H4 * 9 * SITES; s += 256) {
        int i = s % SITES, m = s / SITES;
        int c4 = m % H4, k = m / H4;
        int row = s_nbr[k][i];
        float4 v = make_float4(0.f, 0.f, 0.f, 0.f);
        if (row >= 0)
          v = *(const float4*)(in + (size_t)row * Cin + c0 + c4 * 4);
        s_a[(c4 * 4 + 0) * 9 + k][i] = v.x;
        s_a[(c4 * 4 + 1) * 9 + k][i] = v.y;
        s_a[(c4 * 4 + 2) * 9 + k][i] = v.z;
        s_a[(c4 * 4 + 3) * 9 + k][i] = v.w;
      }
    }
    __syncthreads();
#pragma unroll
    for (int kk = 0; kk < KSL; ++kk) {
      float av[SPT];
      if constexpr (SPT == 4) {
        float4 a4 = *(const float4*)&s_a[kk][si0];
        av[0] = a4.x; av[1] = a4.y; av[2] = a4.z; av[3] = a4.w;
      } else {
        float2 a2 = *(const float2*)&s_a[kk][si0];
        av[0] = a2.x; av[1] = a2.y;
      }
      float wv[OPT];
      if constexpr (OPT == 8) {
        float4 w4a = *(const float4*)&s_w[kk][oc0];
        float4 w4b = *(const float4*)&s_w[kk][OCB / 2 + oc0];
        wv[0] = w4a.x; wv[1] = w4a.y; wv[2] = w4a.z; wv[3] = w4a.w;
        wv[4] = w4b.x; wv[5] = w4b.y; wv[6] = w4b.z; wv[7] = w4b.w;
      } else {
        float4 w4 = *(const float4*)&s_w[kk][oc0];
        wv[0] = w4.x; wv[1] = w4.y; wv[2] = w4.z; wv[3] = w4.w;
      }
#pragma unroll
      for (int a = 0; a < SPT; ++a)
#pragma unroll
        for (int j = 0; j < OPT; ++j)
          acc[a][j] = fmaf(av[a], wv[j], acc[a][j]);
    }
    __syncthreads();
  }
  float bz[OPT];
#pragma unroll
  for (int j = 0; j < OPT; ++j) {
    int oj = (OPT == 8) ? ((j < 4) ? (oc0 + j) : (OCB / 2 + oc0 + j - 4))
                        : (oc0 + j);
    bz[j] = bias[ocb + oj];
  }
#pragma unroll
  for (int a = 0; a < SPT; ++a) {
    int gi = base + si0 + a;
    if (gi < n) {
      float* po = out + (size_t)gi * Cout + ocb;
      if constexpr (OPT == 8) {
        float4 v0, v1;
        v0.x = fmaxf(acc[a][0] + bz[0], 0.f); v0.y = fmaxf(acc[a][1] + bz[1], 0.f);
        v0.z = fmaxf(acc[a][2] + bz[2], 0.f); v0.w = fmaxf(acc[a][3] + bz[3], 0.f);
        v1.x = fmaxf(acc[a][4] + bz[4], 0.f); v1.y = fmaxf(acc[a][5] + bz[5], 0.f);
        v1.z = fmaxf(acc[a][6] + bz[6], 0.f); v1.w = fmaxf(acc[a][7] + bz[7], 0.f);
        *(float4*)(po + oc0) = v0;
        *(float4*)(po + OCB / 2 + oc0) = v1;
      } else {
        float4 v;
        v.x = fmaxf(acc[a][0] + bz[0], 0.f); v.y = fmaxf(acc[a][1] + bz[1], 0.f);
        v.z = fmaxf(acc[a][2] + bz[2], 0.f); v.w = fmaxf(acc[a][3] + bz[3], 0.f);
        *(float4*)(po + oc0) = v;
      }
    }
  }
}

// ------------------------------------------------------------------ bf16x3 32x32x16 MFMA gather-GEMM (L5-L13, RAW K-split)
// r14: K-chunk 32 (2 sub-chunks staged per phase) -> phases halve, 48 MFMAs
// between barriers, T14 prefetch latency budget ~2x. r13 phase-rate analysis:
// 5700 cyc/phase vs 1536 cyc of pipe work -> loaded-memory latency on the
// 1-phase prefetch chain dominated; bigger phases amortize it.
// Prefetch = 12 float4 (48 VGPR); accs live in AGPRs (r13: VGPR_Count 76).
// launch_bounds(256,2) caps VGPR at 128 (r9 cliff lesson).
// C/D (m74/m101): col=lane&31 (oc), row=(reg&3)+8*(reg>>2)+4*(lane>>5).
__global__ __launch_bounds__(256, 2) void gmfma32_k(
    const unsigned short* __restrict__ AH, const unsigned short* __restrict__ AM,
    const unsigned short* __restrict__ AL, float* __restrict__ outP,
    const unsigned short* __restrict__ WX, const int* __restrict__ nbr,
    const int* __restrict__ nactp, int Cin, int Cout, int Nmax, int cinCnt,
    int nocb) {
  __shared__ int s_nbr[9][128];
  __shared__ __align__(16) unsigned short s_a[2][3][2][128][8];  // [sub][piece][kh][row][8]
  __shared__ __align__(16) unsigned short s_w[2][3][2][128][8];
  const int n = nactp[0];
  const int gid = blockIdx.x;
  const int xcd = gid & 7, pos = gid >> 3;
  const int ocbI = pos % nocb;
  const int sb = (pos / nocb) * 8 + xcd;
  const int base = sb * 128;
  if (base >= n) return;
  const int ocb = ocbI * 128;
  const int t = threadIdx.x;
  for (int s = t; s < 1152; s += 256) {
    int i = s & 127, k = s >> 7;
    s_nbr[k][i] = (base + i < n) ? nbr[k * Nmax + base + i] : -1;
  }
  const int l = t & 63;
  const int wm = (t >> 6) & 1, wn = t >> 7;
  const int kh = l >> 5, lr = l & 31;
  const int skh = t >> 7, ssi = t & 127;   // staging slot: (khalf, site/oc)
  f32x16 acc[2][2];
#pragma unroll
  for (int a = 0; a < 2; ++a)
#pragma unroll
    for (int b = 0; b < 2; ++b)
#pragma unroll
      for (int r = 0; r < 16; ++r) acc[a][b][r] = 0.f;
  __syncthreads();
  const int cinStart = blockIdx.z * cinCnt;
  const int nck = cinCnt >> 5;                 // 32-ch chunks per tap
  const int np = 9 * nck;
  const size_t pstride = (size_t)9 * Cout * Cin;   // piece stride in wx
  const size_t kstrideW = (size_t)Cout * Cin;      // tap stride in wx
  const unsigned short* Wth = WX + ((size_t)(ocb + ssi)) * Cin + skh * 8;
  const float4 z4 = make_float4(0.f, 0.f, 0.f, 0.f);
  float4 pw[6], pa[6];
  // prologue: prefetch chunk 0 (k=0, c0=cinStart), both 16-ch subs
  {
#pragma unroll
    for (int sc = 0; sc < 2; ++sc) {
      const unsigned short* W0 = Wth + cinStart + sc * 16;
      pw[sc * 3 + 0] = *(const float4*)(W0);
      pw[sc * 3 + 1] = *(const float4*)(W0 + pstride);
      pw[sc * 3 + 2] = *(const float4*)(W0 + 2 * pstride);
    }
    int row = s_nbr[0][ssi];
    if (row >= 0) {
#pragma unroll
      for (int sc = 0; sc < 2; ++sc) {
        const size_t off = (size_t)row * Cin + cinStart + sc * 16 + skh * 8;
        pa[sc * 3 + 0] = *(const float4*)(AH + off);
        pa[sc * 3 + 1] = *(const float4*)(AM + off);
        pa[sc * 3 + 2] = *(const float4*)(AL + off);
      }
    } else {
#pragma unroll
      for (int q = 0; q < 6; ++q) pa[q] = z4;
    }
  }
  int k = 0, cc = 0;
  for (int ph = 0; ph < np; ++ph) {
    __syncthreads();                       // prior phase frag reads complete
#pragma unroll
    for (int sc = 0; sc < 2; ++sc) {       // vmcnt wait for prefetch lands here
      *(float4*)&s_w[sc][0][skh][ssi][0] = pw[sc * 3 + 0];
      *(float4*)&s_w[sc][1][skh][ssi][0] = pw[sc * 3 + 1];
      *(float4*)&s_w[sc][2][skh][ssi][0] = pw[sc * 3 + 2];
      *(float4*)&s_a[sc][0][skh][ssi][0] = pa[sc * 3 + 0];
      *(float4*)&s_a[sc][1][skh][ssi][0] = pa[sc * 3 + 1];
      *(float4*)&s_a[sc][2][skh][ssi][0] = pa[sc * 3 + 2];
    }
    __syncthreads();                       // staging visible
    // issue next phase's staging loads (latency hides under 48 MFMAs below)
    int cc2 = cc + 1, k2 = k;
    if (cc2 == nck) { cc2 = 0; ++k2; }
    if (ph + 1 < np) {
      const int c0n = cinStart + (cc2 << 5);
      const unsigned short* W0b = Wth + (size_t)k2 * kstrideW + c0n;
      int row = s_nbr[k2][ssi];
#pragma unroll
      for (int sc = 0; sc < 2; ++sc) {
        const unsigned short* W0 = W0b + sc * 16;
        pw[sc * 3 + 0] = *(const float4*)(W0);
        pw[sc * 3 + 1] = *(const float4*)(W0 + pstride);
        pw[sc * 3 + 2] = *(const float4*)(W0 + 2 * pstride);
      }
      if (row >= 0) {
#pragma unroll
        for (int sc = 0; sc < 2; ++sc) {
          const size_t off = (size_t)row * Cin + c0n + sc * 16 + skh * 8;
          pa[sc * 3 + 0] = *(const float4*)(AH + off);
          pa[sc * 3 + 1] = *(const float4*)(AM + off);
          pa[sc * 3 + 2] = *(const float4*)(AL + off);
        }
      } else {
#pragma unroll
        for (int q = 0; q < 6; ++q) pa[q] = z4;
      }
    }
    k = k2; cc = cc2;
    // frag reads + MFMA, both 16-ch sub-chunks
#pragma unroll
    for (int sc = 0; sc < 2; ++sc) {
      bf8v af[2][3], wf[2][3];
#pragma unroll
      for (int mi = 0; mi < 2; ++mi)
#pragma unroll
        for (int p = 0; p < 3; ++p)
          af[mi][p] = *(const bf8v*)&s_a[sc][p][kh][wm * 64 + mi * 32 + lr][0];
#pragma unroll
      for (int ni = 0; ni < 2; ++ni)
#pragma unroll
        for (int p = 0; p < 3; ++p)
          wf[ni][p] = *(const bf8v*)&s_w[sc][p][kh][wn * 64 + ni * 32 + lr][0];
#pragma unroll
      for (int mi = 0; mi < 2; ++mi)
#pragma unroll
        for (int ni = 0; ni < 2; ++ni) {
          f32x16 c = acc[mi][ni];
          c = __builtin_amdgcn_mfma_f32_32x32x16_bf16(af[mi][0], wf[ni][0], c, 0, 0, 0);
          c = __builtin_amdgcn_mfma_f32_32x32x16_bf16(af[mi][0], wf[ni][1], c, 0, 0, 0);
          c = __builtin_amdgcn_mfma_f32_32x32x16_bf16(af[mi][1], wf[ni][0], c, 0, 0, 0);
          c = __builtin_amdgcn_mfma_f32_32x32x16_bf16(af[mi][1], wf[ni][1], c, 0, 0, 0);
          c = __builtin_amdgcn_mfma_f32_32x32x16_bf16(af[mi][0], wf[ni][2], c, 0, 0, 0);
          c = __builtin_amdgcn_mfma_f32_32x32x16_bf16(af[mi][2], wf[ni][0], c, 0, 0, 0);
          acc[mi][ni] = c;
        }
    }
  }
  float* ob = outP + (size_t)blockIdx.z * Nmax * Cout;
#pragma unroll
  for (int mi = 0; mi < 2; ++mi) {
    const int sbase = base + wm * 64 + mi * 32 + 4 * kh;
#pragma unroll
    for (int ni = 0; ni < 2; ++ni) {
      const int oc = ocb + wn * 64 + ni * 32 + lr;
#pragma unroll
      for (int reg = 0; reg < 16; ++reg) {
        int gi = sbase + (reg & 3) + 8 * (reg >> 2);
        if (gi < n) ob[(size_t)gi * Cout + oc] = acc[mi][ni][reg];
      }
    }
  }
}

// ------------------------------------------------------------------ K-split combine (+bias+relu; optional f32 out; optional bf16x3 planes)
__global__ __launch_bounds__(256) void combine_k(const float* __restrict__ P,
    float* __restrict__ out, const float* __restrict__ bias,
    const int* __restrict__ nactp, int C, int S, int sliceStride,
    unsigned short* __restrict__ oh, unsigned short* __restrict__ om,
    unsigned short* __restrict__ ol) {
  int tg = blockIdx.x * 256 + threadIdx.x;
  int cg = C >> 2;
  int j = tg / cg, c4 = tg % cg;
  if (j >= nactp[0]) return;
  size_t o = (size_t)j * C + c4 * 4;
  float4 v = *(const float4*)(bias + c4 * 4);
  for (int s = 0; s < S; ++s) {
    float4 u = *(const float4*)(P + (size_t)s * sliceStride + o);
    v.x += u.x; v.y += u.y; v.z += u.z; v.w += u.w;
  }
  v.x = fmaxf(v.x, 0.f); v.y = fmaxf(v.y, 0.f);
  v.z = fmaxf(v.z, 0.f); v.w = fmaxf(v.w, 0.f);
  if (out) *(float4*)(out + o) = v;
  if (oh) {
    const float* pv = &v.x;
#pragma unroll
    for (int u = 0; u < 4; ++u) {
      float y = pv[u];
      unsigned short h = f2bf(y);
      float r1 = y - bf2f(h);
      unsigned short m2 = f2bf(r1);
      float r2 = r1 - bf2f(m2);
      oh[o + u] = h; om[o + u] = m2; ol[o + u] = f2bf(r2);
    }
  }
}

// ------------------------------------------------------------------ compact 2x2 maxpool (optional bf16x3 planes)
__global__ __launch_bounds__(256) void pool_c_k(const float* __restrict__ inF,
    float* __restrict__ outF, const int* __restrict__ listC,
    const int* __restrict__ imF, const int* __restrict__ nactp, int Hf, int C,
    unsigned short* __restrict__ oh, unsigned short* __restrict__ om,
    unsigned short* __restrict__ ol) {
  int tg = blockIdx.x * 256 + threadIdx.x;
  int cg = C >> 2;
  int j = tg / cg, c4 = tg % cg;
  if (j >= nactp[0]) return;
  int code = listC[j];
  int b = code >> 20, Y = (code >> 10) & 1023, X = code & 1023;
  float4 v = make_float4(0.f, 0.f, 0.f, 0.f);
#pragma unroll
  for (int dy = 0; dy < 2; ++dy)
#pragma unroll
    for (int dx = 0; dx < 2; ++dx) {
      int ci = imF[((size_t)b * Hf + 2 * Y + dy) * Hf + 2 * X + dx];
      if (ci >= 0) {
        float4 u = *(const float4*)(inF + (size_t)ci * C + c4 * 4);
        v.x = fmaxf(v.x, u.x); v.y = fmaxf(v.y, u.y);
        v.z = fmaxf(v.z, u.z); v.w = fmaxf(v.w, u.w);
      }
    }
  size_t o = (size_t)j * C + c4 * 4;
  *(float4*)(outF + o) = v;
  if (oh) {
    const float* pv = &v.x;
#pragma unroll
    for (int u = 0; u < 4; ++u) {
      float y = pv[u];
      unsigned short h = f2bf(y);
      float r1 = y - bf2f(h);
      unsigned short m2 = f2bf(r1);
      float r2 = r1 - bf2f(m2);
      oh[o + u] = h; om[o + u] = m2; ol[o + u] = f2bf(r2);
    }
  }
}

// ------------------------------------------------------------------ final pool -> dense [2,512,16,16]
__global__ __launch_bounds__(256) void pool_d_k(const float* __restrict__ inF,
    float* __restrict__ outD, const int* __restrict__ im32) {
  int tg = blockIdx.x * 256 + threadIdx.x;
  int c4 = tg & 127;
  int rest = tg >> 7;
  int X = rest & 15, Y = (rest >> 4) & 15, b = rest >> 8;
  float4 v = make_float4(0.f, 0.f, 0.f, 0.f);
#pragma unroll
  for (int dy = 0; dy < 2; ++dy)
#pragma unroll
    for (int dx = 0; dx < 2; ++dx) {
      int ci = im32[((size_t)b * 32 + 2 * Y + dy) * 32 + 2 * X + dx];
      if (ci >= 0) {
        float4 u = *(const float4*)(inF + (size_t)ci * 512 + c4 * 4);
        v.x = fmaxf(v.x, u.x); v.y = fmaxf(v.y, u.y);
        v.z = fmaxf(v.z, u.z); v.w = fmaxf(v.w, u.w);
      }
    }
  const float* pv = &v.x;
#pragma unroll
  for (int u = 0; u < 4; ++u) {
    int c = c4 * 4 + u;
    outD[(((size_t)b * 512 + c) * 16 + Y) * 16 + X] = pv[u];
  }
}

// ------------------------------------------------------------------ fully connected
template <bool RELU>
__global__ __launch_bounds__(256) void fc_k(const float* __restrict__ in,
                                            const float* __restrict__ w,
                                            const float* __restrict__ bias,
                                            float* __restrict__ out, int K,
                                            int R) {
  const int r = blockIdx.x;
  const int t = threadIdx.x;
  const float* wr = w + (size_t)r * K;
  float a0 = 0.f, a1 = 0.f;
  for (int k = t * 4; k < K; k += 1024) {
    float4 wv = *(const float4*)(wr + k);
    float4 x0 = *(const float4*)(in + k);
    float4 x1 = *(const float4*)(in + K + k);
    a0 += wv.x * x0.x + wv.y * x0.y + wv.z * x0.z + wv.w * x0.w;
    a1 += wv.x * x1.x + wv.y * x1.y + wv.z * x1.z + wv.w * x1.w;
  }
#pragma unroll
  for (int off = 32; off > 0; off >>= 1) {
    a0 += __shfl_down(a0, off);
    a1 += __shfl_down(a1, off);
  }
  __shared__ float s0[4], s1[4];
  const int lane = t & 63, wid = t >> 6;
  if (lane == 0) { s0[wid] = a0; s1[wid] = a1; }
  __syncthreads();
  if (t == 0) {
    float v0 = s0[0] + s0[1] + s0[2] + s0[3] + bias[r];
    float v1 = s1[0] + s1[1] + s1[2] + s1[3] + bias[r];
    if (RELU) { v0 = fmaxf(v0, 0.f); v1 = fmaxf(v1, 0.f); }
    out[r] = v0;
    out[R + r] = v1;
  }
}

// ------------------------------------------------------------------ launch
extern "C" void kernel_launch(void* const* d_in, const int* in_sizes, int n_in,
                              void* d_out, int out_size, void* d_ws,
                              size_t ws_size, hipStream_t stream) {
  (void)in_sizes; (void)n_in; (void)out_size; (void)ws_size;
  const float* x = (const float*)d_in[0];
  const float* Wc[14];
  const float* Bc[14];
  for (int i = 1; i <= 13; ++i) {
    Wc[i] = (const float*)d_in[2 * i - 1];
    Bc[i] = (const float*)d_in[2 * i];
  }
  const float* fw1 = (const float*)d_in[27];
  const float* fb1 = (const float*)d_in[28];
  const float* fw2 = (const float*)d_in[29];
  const float* fb2 = (const float*)d_in[30];
  const float* fw3 = (const float*)d_in[31];
  const float* fb3 = (const float*)d_in[32];
  const float* fw4 = (const float*)d_in[33];
  const float* fb4 = (const float*)d_in[34];

  static const int CH[14] = {1, 64, 64, 128, 128, 256, 256, 256,
                             512, 512, 512, 512, 512, 512};

  char* ws = (char*)d_ws;
  size_t cur = 0;
  auto alloc = [&](size_t bytes) {
    size_t o = cur;
    cur += (bytes + 255) & ~(size_t)255;
    return o;
  };
  // fp32 weight transposes (L1-L4)
  size_t wtOff[5];
  for (int i = 1; i <= 4; ++i)
    wtOff[i] = alloc((size_t)CH[i] * CH[i - 1] * 9 * 4);
  float* wT[5];
  for (int i = 1; i <= 4; ++i) wT[i] = (float*)(ws + wtOff[i]);
  // bf16x3 weight planes (L5-L13): layout [p][k][oc][cin]
  unsigned short* wX[14];
  for (int i = 5; i <= 13; ++i)
    wX[i] = (unsigned short*)(ws + alloc((size_t)3 * 9 * CH[i] * CH[i - 1] * 2));
  // features. Praw (K-split partials, contiguous from A1) may extend through
  // A5 (dead after L7 pool): L5-7 need 42MB (< A1..P4 63.9MB), L8-10 z=4 need
  // 67.1MB (< A1..A5 84.9MB), L11-13 33.6MB.
  float* F0  = (float*)(ws + alloc((size_t)NMAX512 * 1 * 4));
  size_t a1Off = alloc((size_t)NMAX512 * 64 * 4);
  float* A1  = (float*)(ws + a1Off);
  float* Praw = A1;
  float* A2  = (float*)(ws + alloc((size_t)NMAX512 * 64 * 4));
  float* P2  = (float*)(ws + alloc((size_t)NMAX256 * 64 * 4));
  float* A3  = (float*)(ws + alloc((size_t)NMAX256 * 128 * 4));
  float* A4  = (float*)(ws + alloc((size_t)NMAX256 * 128 * 4));
  float* P4  = (float*)(ws + alloc((size_t)NMAX128 * 128 * 4));
  float* A5  = (float*)(ws + alloc((size_t)NMAX128 * 256 * 4));
  float* P7  = (float*)(ws + alloc((size_t)NMAX64 * 256 * 4));
  float* A8  = (float*)(ws + alloc((size_t)NMAX64 * 512 * 4));
  float* P10 = (float*)(ws + alloc((size_t)NMAX32 * 512 * 4));
  float* A11 = (float*)(ws + alloc((size_t)NMAX32 * 512 * 4));
  float* D13 = (float*)(ws + alloc((size_t)NB * 512 * 16 * 16 * 4));
  float* F1  = (float*)(ws + alloc(NB * 1024 * 4));
  float* F2  = (float*)(ws + alloc(NB * 512 * 4));
  float* F3  = (float*)(ws + alloc(NB * 256 * 4));
  // bf16x3 feature plane arenas (ping-pong X/Y)
  const size_t PLE = (size_t)NMAX128 * 256;
  unsigned short* XH = (unsigned short*)(ws + alloc(PLE * 2));
  unsigned short* XM = (unsigned short*)(ws + alloc(PLE * 2));
  unsigned short* XL = (unsigned short*)(ws + alloc(PLE * 2));
  unsigned short* YH = (unsigned short*)(ws + alloc(PLE * 2));
  unsigned short* YM = (unsigned short*)(ws + alloc(PLE * 2));
  unsigned short* YL = (unsigned short*)(ws + alloc(PLE * 2));
  // index maps / lists / neighbor tables / counters
  int* im512 = (int*)(ws + alloc((size_t)NB * 512 * 512 * 4));
  int* im256 = (int*)(ws + alloc((size_t)NB * 256 * 256 * 4));
  int* im128 = (int*)(ws + alloc((size_t)NB * 128 * 128 * 4));
  int* im64  = (int*)(ws + alloc((size_t)NB * 64 * 64 * 4));
  int* im32  = (int*)(ws + alloc((size_t)NB * 32 * 32 * 4));
  int* l512 = (int*)(ws + alloc((size_t)NMAX512 * 4));
  int* l256 = (int*)(ws + alloc((size_t)NMAX256 * 4));
  int* l128 = (int*)(ws + alloc((size_t)NMAX128 * 4));
  int* l64  = (int*)(ws + alloc((size_t)NMAX64 * 4));
  int* l32  = (int*)(ws + alloc((size_t)NMAX32 * 4));
  int* nb512 = (int*)(ws + alloc((size_t)9 * NMAX512 * 4));
  int* nb256 = (int*)(ws + alloc((size_t)9 * NMAX256 * 4));
  int* nb128 = (int*)(ws + alloc((size_t)9 * NMAX128 * 4));
  int* nb64  = (int*)(ws + alloc((size_t)9 * NMAX64 * 4));
  int* nb32  = (int*)(ws + alloc((size_t)9 * NMAX32 * 4));
  int* nact = (int*)(ws + alloc(256));

  const dim3 blk(256);
  hipMemsetAsync(nact, 0, 32, stream);

  // ---- lists / index maps / neighbors
  hipLaunchKernelGGL(build_l0_k, dim3(2048), blk, 0, stream, x, l512, im512, F0, nact + 0, NB * 512 * 512, NMAX512);
  hipLaunchKernelGGL(build_pl_k, dim3(512), blk, 0, stream, im512, l256, im256, nact + 1, 256, NMAX256);
  hipLaunchKernelGGL(build_pl_k, dim3(128), blk, 0, stream, im256, l128, im128, nact + 2, 128, NMAX128);
  hipLaunchKernelGGL(build_pl_k, dim3(32), blk, 0, stream, im128, l64, im64, nact + 3, 64, NMAX64);
  hipLaunchKernelGGL(build_pl_k, dim3(8), blk, 0, stream, im64, l32, im32, nact + 4, 32, NMAX32);
  hipLaunchKernelGGL(build_nbr_k, dim3(NMAX512 / 256), blk, 0, stream, l512, im512, nact + 0, nb512, 512, NMAX512);
  hipLaunchKernelGGL(build_nbr_k, dim3(NMAX256 / 256), blk, 0, stream, l256, im256, nact + 1, nb256, 256, NMAX256);
  hipLaunchKernelGGL(build_nbr_k, dim3(NMAX128 / 256), blk, 0, stream, l128, im128, nact + 2, nb128, 128, NMAX128);
  hipLaunchKernelGGL(build_nbr_k, dim3(NMAX64 / 256), blk, 0, stream, l64, im64, nact + 3, nb64, 64, NMAX64);
  hipLaunchKernelGGL(build_nbr_k, dim3(NMAX32 / 256), blk, 0, stream, l32, im32, nact + 4, nb32, 32, NMAX32);

  // ---- weight prep
  for (int i = 1; i <= 4; ++i) {
    int R = CH[i], C = CH[i - 1] * 9;
    hipLaunchKernelGGL(transpose_k, dim3((C + 31) / 32, (R + 31) / 32), blk, 0,
                       stream, Wc[i], wT[i], R, C);
  }
  for (int i = 5; i <= 13; ++i) {
    int e = CH[i] * CH[i - 1];
    hipLaunchKernelGGL(wprep_k, dim3((e + 255) / 256), blk, 0, stream, Wc[i],
                       wX[i], CH[i], CH[i - 1]);
  }

  // ---- L1-L4 (fp32 path)
  hipLaunchKernelGGL((gconv_k<1, 64, 64, 4, 4>), dim3(512, 1, 1), blk, 0, stream,
                     F0, A1, wT[1], Bc[1], nb512, nact + 0, 1, 64, NMAX512, 1, 1);
  hipLaunchKernelGGL((gconv_k<8, 64, 64, 4, 4>), dim3(512, 1, 1), blk, 0, stream,
                     A1, A2, wT[2], Bc[2], nb512, nact + 0, 64, 64, NMAX512, 64, 1);
  hipLaunchKernelGGL(pool_c_k, dim3(NMAX256 * 16 / 256), blk, 0, stream, A2, P2,
                     l256, im512, nact + 1, 512, 64, (unsigned short*)nullptr,
                     (unsigned short*)nullptr, (unsigned short*)nullptr);
  hipLaunchKernelGGL((gconv_k<8, 64, 128, 4, 8>), dim3(448, 1, 1), blk, 0, stream,
                     P2, A3, wT[3], Bc[3], nb256, nact + 1, 64, 128, NMAX256, 64, 1);
  hipLaunchKernelGGL((gconv_k<8, 64, 128, 4, 8>), dim3(448, 1, 1), blk, 0, stream,
                     A3, A4, wT[4], Bc[4], nb256, nact + 1, 128, 128, NMAX256, 128, 1);
  hipLaunchKernelGGL(pool_c_k, dim3(NMAX128 * 32 / 256), blk, 0, stream, A4, P4,
                     l128, im256, nact + 2, 256, 128, XH, XM, XL);

  // ---- L5-L13 (bf16x3 32x32 MFMA, K-chunk 32, RAW K-split -> Praw + combine)
  unsigned short* NUL = nullptr;
  const int SL128 = NMAX128 * 256;
  const int SL64  = NMAX64 * 512;
  const int SL32  = NMAX32 * 512;
  // L5: 128->256 @128, z=2 (cinCnt 64)
  hipLaunchKernelGGL(gmfma32_k, dim3(320, 1, 2), blk, 0, stream,
                     XH, XM, XL, Praw, wX[5], nb128, nact + 2, 128, 256, NMAX128, 64, 2);
  hipLaunchKernelGGL(combine_k, dim3(NMAX128 * 64 / 256), blk, 0, stream, Praw,
                     (float*)nullptr, Bc[5], nact + 2, 256, 2, SL128, YH, YM, YL);
  // L6: 256->256 @128, z=2 (cinCnt 128)
  hipLaunchKernelGGL(gmfma32_k, dim3(320, 1, 2), blk, 0, stream,
                     YH, YM, YL, Praw, wX[6], nb128, nact + 2, 256, 256, NMAX128, 128, 2);
  hipLaunchKernelGGL(combine_k, dim3(NMAX128 * 64 / 256), blk, 0, stream, Praw,
                     (float*)nullptr, Bc[6], nact + 2, 256, 2, SL128, XH, XM, XL);
  // L7: 256->256 @128, z=2 -> f32 only (feeds pool)
  hipLaunchKernelGGL(gmfma32_k, dim3(320, 1, 2), blk, 0, stream,
                     XH, XM, XL, Praw, wX[7], nb128, nact + 2, 256, 256, NMAX128, 128, 2);
  hipLaunchKernelGGL(combine_k, dim3(NMAX128 * 64 / 256), blk, 0, stream, Praw,
                     A5, Bc[7], nact + 2, 256, 2, SL128, NUL, NUL, NUL);
  hipLaunchKernelGGL(pool_c_k, dim3(NMAX64 * 64 / 256), blk, 0, stream, A5, P7,
                     l64, im128, nact + 3, 128, 256, XH, XM, XL);
  // L8: 256->512 @64, z=4 (cinCnt 64)
  hipLaunchKernelGGL(gmfma32_k, dim3(256, 1, 4), blk, 0, stream,
                     XH, XM, XL, Praw, wX[8], nb64, nact + 3, 256, 512, NMAX64, 64, 4);
  hipLaunchKernelGGL(combine_k, dim3(NMAX64 * 128 / 256), blk, 0, stream, Praw,
                     (float*)nullptr, Bc[8], nact + 3, 512, 4, SL64, YH, YM, YL);
  // L9: 512->512 @64, z=4 (cinCnt 128)
  hipLaunchKernelGGL(gmfma32_k, dim3(256, 1, 4), blk, 0, stream,
                     YH, YM, YL, Praw, wX[9], nb64, nact + 3, 512, 512, NMAX64, 128, 4);
  hipLaunchKernelGGL(combine_k, dim3(NMAX64 * 128 / 256), blk, 0, stream, Praw,
                     (float*)nullptr, Bc[9], nact + 3, 512, 4, SL64, XH, XM, XL);
  // L10: 512->512 @64, z=4 -> f32 only (feeds pool)
  hipLaunchKernelGGL(gmfma32_k, dim3(256, 1, 4), blk, 0, stream,
                     XH, XM, XL, Praw, wX[10], nb64, nact + 3, 512, 512, NMAX64, 128, 4);
  hipLaunchKernelGGL(combine_k, dim3(NMAX64 * 128 / 256), blk, 0, stream, Praw,
                     A8, Bc[10], nact + 3, 512, 4, SL64, NUL, NUL, NUL);
  hipLaunchKernelGGL(pool_c_k, dim3(NMAX32 * 128 / 256), blk, 0, stream, A8, P10,
                     l32, im64, nact + 4, 64, 512, XH, XM, XL);
  // L11-13: 512->512 @32, z=8 (cinCnt 64)
  hipLaunchKernelGGL(gmfma32_k, dim3(64, 1, 8), blk, 0, stream,
                     XH, XM, XL, Praw, wX[11], nb32, nact + 4, 512, 512, NMAX32, 64, 4);
  hipLaunchKernelGGL(combine_k, dim3(NMAX32 * 128 / 256), blk, 0, stream, Praw,
                     (float*)nullptr, Bc[11], nact + 4, 512, 8, SL32, YH, YM, YL);
  hipLaunchKernelGGL(gmfma32_k, dim3(64, 1, 8), blk, 0, stream,
                     YH, YM, YL, Praw, wX[12], nb32, nact + 4, 512, 512, NMAX32, 64, 4);
  hipLaunchKernelGGL(combine_k, dim3(NMAX32 * 128 / 256), blk, 0, stream, Praw,
                     (float*)nullptr, Bc[12], nact + 4, 512, 8, SL32, XH, XM, XL);
  hipLaunchKernelGGL(gmfma32_k, dim3(64, 1, 8), blk, 0, stream,
                     XH, XM, XL, Praw, wX[13], nb32, nact + 4, 512, 512, NMAX32, 64, 4);
  hipLaunchKernelGGL(combine_k, dim3(NMAX32 * 128 / 256), blk, 0, stream, Praw,
                     A11, Bc[13], nact + 4, 512, 8, SL32, NUL, NUL, NUL);
  hipLaunchKernelGGL(pool_d_k, dim3(256), blk, 0, stream, A11, D13, im32);

  // ---- MLP
  hipLaunchKernelGGL((fc_k<true>), dim3(1024), blk, 0, stream, D13, fw1, fb1, F1, 131072, 1024);
  hipLaunchKernelGGL((fc_k<true>), dim3(512), blk, 0, stream, F1, fw2, fb2, F2, 1024, 512);
  hipLaunchKernelGGL((fc_k<true>), dim3(256), blk, 0, stream, F2, fw3, fb3, F3, 512, 256);
  hipLaunchKernelGGL((fc_k<false>), dim3(2), blk, 0, stream, F3, fw4, fb4, (float*)d_out, 256, 2);
}

// Round 15
// 2178.131 us; speedup vs baseline: 1.3662x; 1.3662x over previous
//
#include <hip/hip_runtime.h>
#include <hip/hip_bf16.h>
#include <cstddef>
#include <cstdint>

#define NB 2

#define NMAX512 32768
#define NMAX256 28672
#define NMAX128 20480
#define NMAX64  8192
#define NMAX32  2048

typedef __attribute__((ext_vector_type(8))) short bf8v;    // 8 bf16 = 4 VGPR
typedef __attribute__((ext_vector_type(4))) float f32x4;
typedef __attribute__((ext_vector_type(16))) float f32x16;

static __device__ __forceinline__ unsigned short f2bf(float x) {
  __hip_bfloat16 h = __float2bfloat16(x);
  return *reinterpret_cast<unsigned short*>(&h);
}
static __device__ __forceinline__ float bf2f(unsigned short u) {
  __hip_bfloat16 h;
  *reinterpret_cast<unsigned short*>(&h) = u;
  return __bfloat162float(h);
}

// ------------------------------------------------------------------ list build (res 512 from x, Cin=1)
__global__ __launch_bounds__(256) void build_l0_k(const float* __restrict__ x,
    int* __restrict__ list, int* __restrict__ im, float* __restrict__ f0,
    int* __restrict__ nact, int total, int nmax) {
  int i = blockIdx.x * 256 + threadIdx.x;
  bool act = false;
  float v = 0.f;
  if (i < total) { v = x[i]; act = (v != 0.f); }
  unsigned long long mb = __ballot(act);
  int lane = threadIdx.x & 63;
  int prefix = __popcll(mb & ((1ull << lane) - 1));
  int base = 0;
  if (lane == 0) base = atomicAdd(nact, __popcll(mb));
  base = __shfl(base, 0);
  if (i < total) {
    int idx = act ? (base + prefix) : -1;
    if (idx >= nmax) idx = -1;
    im[i] = idx;
    if (idx >= 0) {
      int b = i >> 18;
      int rem = i & 262143;
      list[idx] = (b << 20) | ((rem >> 9) << 10) | (rem & 511);
      f0[idx] = v;
    }
  }
}

// ------------------------------------------------------------------ pooled list from finer idxmap
__global__ __launch_bounds__(256) void build_pl_k(const int* __restrict__ imF,
    int* __restrict__ list, int* __restrict__ im, int* __restrict__ nact,
    int Hc, int nmax) {
  int total = NB * Hc * Hc;
  int i = blockIdx.x * 256 + threadIdx.x;
  bool act = false;
  int b = 0, y = 0, x = 0;
  int Hf = Hc * 2;
  if (i < total) {
    x = i % Hc; y = (i / Hc) % Hc; b = i / (Hc * Hc);
    const int* p = imF + ((size_t)b * Hf + 2 * y) * Hf + 2 * x;
    act = (p[0] >= 0) || (p[1] >= 0) || (p[Hf] >= 0) || (p[Hf + 1] >= 0);
  }
  unsigned long long mb = __ballot(act);
  int lane = threadIdx.x & 63;
  int prefix = __popcll(mb & ((1ull << lane) - 1));
  int base = 0;
  if (lane == 0) base = atomicAdd(nact, __popcll(mb));
  base = __shfl(base, 0);
  if (i < total) {
    int idx = act ? (base + prefix) : -1;
    if (idx >= nmax) idx = -1;
    im[i] = idx;
    if (idx >= 0) list[idx] = (b << 20) | (y << 10) | x;
  }
}

// ------------------------------------------------------------------ 9-neighbor index table
__global__ __launch_bounds__(256) void build_nbr_k(const int* __restrict__ list,
    const int* __restrict__ im, const int* __restrict__ nactp,
    int* __restrict__ nbr, int H, int nmax) {
  int i = blockIdx.x * 256 + threadIdx.x;
  if (i >= nactp[0]) return;
  int code = list[i];
  int b = code >> 20, y = (code >> 10) & 1023, x = code & 1023;
#pragma unroll
  for (int k = 0; k < 9; ++k) {
    int yy = y + k / 3 - 1, xx = x + k % 3 - 1;
    int v = -1;
    if (yy >= 0 && yy < H && xx >= 0 && xx < H)
      v = im[((size_t)b * H + yy) * H + xx];
    nbr[k * nmax + i] = v;
  }
}

// ------------------------------------------------------------------ weight transpose  [R][C] -> [C][R]   (L1-L4 fp32 path)
__global__ __launch_bounds__(256) void transpose_k(const float* __restrict__ in,
                                                   float* __restrict__ out,
                                                   int R, int C) {
  __shared__ float tile[32][33];
  int bx = blockIdx.x * 32;
  int by = blockIdx.y * 32;
  int tx = threadIdx.x % 32, ty0 = threadIdx.x / 32;
  for (int ty = ty0; ty < 32; ty += 8) {
    int r = by + ty, c = bx + tx;
    tile[ty][tx] = (r < R && c < C) ? in[(size_t)r * C + c] : 0.f;
  }
  __syncthreads();
  for (int ty = ty0; ty < 32; ty += 8) {
    int r = bx + ty, c = by + tx;
    if (r < C && c < R) out[(size_t)r * R + c] = tile[tx][ty];
  }
}

// ------------------------------------------------------------------ weight bf16x3 split  w[Cout][Cin][9] -> wx[p][k][oc][cin]
__global__ __launch_bounds__(256) void wprep_k(const float* __restrict__ w,
                                               unsigned short* __restrict__ wx,
                                               int Cout, int Cin) {
  int i = blockIdx.x * 256 + threadIdx.x;
  if (i >= Cout * Cin) return;
  int oc = i / Cin, ci = i - oc * Cin;
  const float* src = w + ((size_t)oc * Cin + ci) * 9;
  const size_t sk = (size_t)Cout * Cin;
#pragma unroll
  for (int k = 0; k < 9; ++k) {
    float x = src[k];
    unsigned short h = f2bf(x);
    float r1 = x - bf2f(h);
    unsigned short m = f2bf(r1);
    float r2 = r1 - bf2f(m);
    wx[(size_t)k * sk + i] = h;
    wx[(size_t)(9 + k) * sk + i] = m;
    wx[(size_t)(18 + k) * sk + i] = f2bf(r2);
  }
}

// ------------------------------------------------------------------ gather-GEMM fp32 (256 thr, 4x8; L1-L4 only)
template <int CC, int SITES, int OCB, int SPT, int OPT>
__global__ __launch_bounds__(256, 2) void gconv_k(
    const float* __restrict__ in, float* __restrict__ out,
    const float* __restrict__ wT, const float* __restrict__ bias,
    const int* __restrict__ nbr, const int* __restrict__ nactp,
    int Cin, int Cout, int Nmax, int cinCnt, int nocb) {
  constexpr int KSL = CC * 9;
  __shared__ int s_nbr[9][SITES];
  __shared__ float s_a[KSL][SITES];
  __shared__ float s_w[KSL][OCB];
  const int n = nactp[0];
  const int gid = blockIdx.x;
  const int xcd = gid & 7;
  const int pos = gid >> 3;
  const int ocbI = pos % nocb;
  const int sb = (pos / nocb) * 8 + xcd;
  const int base = sb * SITES;
  if (base >= n) return;
  const int ocb = ocbI * OCB;
  const int t = threadIdx.x;
  for (int s = t; s < 9 * SITES; s += 256) {
    int i = s % SITES, k = s / SITES;
    int gi = base + i;
    s_nbr[k][i] = (gi < n) ? nbr[k * Nmax + gi] : -1;
  }
  constexpr int OCG = OCB / OPT;
  const int oc0 = (t % OCG) * 4;
  const int si0 = (t / OCG) * SPT;
  float acc[SPT][OPT];
#pragma unroll
  for (int a = 0; a < SPT; ++a)
#pragma unroll
    for (int j = 0; j < OPT; ++j) acc[a][j] = 0.f;
  __syncthreads();
  const int nch = cinCnt / CC;
  for (int ch = 0; ch < nch; ++ch) {
    const int c0 = ch * CC;
    const float* wrow = wT + ((size_t)c0 * 9) * Cout + ocb;
    for (int s = t; s < KSL * (OCB / 4); s += 256) {
      int j4 = s % (OCB / 4), r = s / (OCB / 4);
      *(float4*)&s_w[r][j4 * 4] = *(const float4*)(wrow + (size_t)r * Cout + j4 * 4);
    }
    if constexpr (CC == 1) {
      for (int s = t; s < 9 * SITES; s += 256) {
        int i = s % SITES, k = s / SITES;
        int row = s_nbr[k][i];
        s_a[k][i] = (row >= 0) ? in[row] : 0.f;
      }
    } else {
      constexpr int H4 = CC / 4;
      for (int s = t; s < H4 * 9 * SITES; s += 256) {
        int i = s % SITES, m = s / SITES;
        int c4 = m % H4, k = m / H4;
        int row = s_nbr[k][i];
        float4 v = make_float4(0.f, 0.f, 0.f, 0.f);
        if (row >= 0)
          v = *(const float4*)(in + (size_t)row * Cin + c0 + c4 * 4);
        s_a[(c4 * 4 + 0) * 9 + k][i] = v.x;
        s_a[(c4 * 4 + 1) * 9 + k][i] = v.y;
        s_a[(c4 * 4 + 2) * 9 + k][i] = v.z;
        s_a[(c4 * 4 + 3) * 9 + k][i] = v.w;
      }
    }
    __syncthreads();
#pragma unroll
    for (int kk = 0; kk < KSL; ++kk) {
      float av[SPT];
      if constexpr (SPT == 4) {
        float4 a4 = *(const float4*)&s_a[kk][si0];
        av[0] = a4.x; av[1] = a4.y; av[2] = a4.z; av[3] = a4.w;
      } else {
        float2 a2 = *(const float2*)&s_a[kk][si0];
        av[0] = a2.x; av[1] = a2.y;
      }
      float wv[OPT];
      if constexpr (OPT == 8) {
        float4 w4a = *(const float4*)&s_w[kk][oc0];
        float4 w4b = *(const float4*)&s_w[kk][OCB / 2 + oc0];
        wv[0] = w4a.x; wv[1] = w4a.y; wv[2] = w4a.z; wv[3] = w4a.w;
        wv[4] = w4b.x; wv[5] = w4b.y; wv[6] = w4b.z; wv[7] = w4b.w;
      } else {
        float4 w4 = *(const float4*)&s_w[kk][oc0];
        wv[0] = w4.x; wv[1] = w4.y; wv[2] = w4.z; wv[3] = w4.w;
      }
#pragma unroll
      for (int a = 0; a < SPT; ++a)
#pragma unroll
        for (int j = 0; j < OPT; ++j)
          acc[a][j] = fmaf(av[a], wv[j], acc[a][j]);
    }
    __syncthreads();
  }
  float bz[OPT];
#pragma unroll
  for (int j = 0; j < OPT; ++j) {
    int oj = (OPT == 8) ? ((j < 4) ? (oc0 + j) : (OCB / 2 + oc0 + j - 4))
                        : (oc0 + j);
    bz[j] = bias[ocb + oj];
  }
#pragma unroll
  for (int a = 0; a < SPT; ++a) {
    int gi = base + si0 + a;
    if (gi < n) {
      float* po = out + (size_t)gi * Cout + ocb;
      if constexpr (OPT == 8) {
        float4 v0, v1;
        v0.x = fmaxf(acc[a][0] + bz[0], 0.f); v0.y = fmaxf(acc[a][1] + bz[1], 0.f);
        v0.z = fmaxf(acc[a][2] + bz[2], 0.f); v0.w = fmaxf(acc[a][3] + bz[3], 0.f);
        v1.x = fmaxf(acc[a][4] + bz[4], 0.f); v1.y = fmaxf(acc[a][5] + bz[5], 0.f);
        v1.z = fmaxf(acc[a][6] + bz[6], 0.f); v1.w = fmaxf(acc[a][7] + bz[7], 0.f);
        *(float4*)(po + oc0) = v0;
        *(float4*)(po + OCB / 2 + oc0) = v1;
      } else {
        float4 v;
        v.x = fmaxf(acc[a][0] + bz[0], 0.f); v.y = fmaxf(acc[a][1] + bz[1], 0.f);
        v.z = fmaxf(acc[a][2] + bz[2], 0.f); v.w = fmaxf(acc[a][3] + bz[3], 0.f);
        *(float4*)(po + oc0) = v;
      }
    }
  }
}

// ------------------------------------------------------------------ bf16x3 32x32x16 MFMA gather-GEMM (L5-L13, RAW K-split)
// r15 = r13 verbatim (best verified config: 2179us total, L9/L10 342us).
// T14 prefetch: phase p+1's 6 global staging loads (3 W + 3 A float4) issued
// into REGISTERS right after phase p's staging barrier; vmcnt wait lands at
// p+1's ds_write, HBM latency hides under p's frag reads + 24 MFMAs.
// REGISTER BUDGET LESSON (r14): gfx950 unified VGPR/AGPR file - 64 acc AGPRs
// + ~76 VGPRs leaves NO room for a 48-reg prefetch under the (256,2) 128-cap;
// r14's 12-float4 prefetch spilled to scratch (WRITE 63MB -> 695MB, 1.4x
// slower). 6-float4 (24 reg) is the fitting depth.
// C/D (m74/m101): col=lane&31 (oc), row=(reg&3)+8*(reg>>2)+4*(lane>>5).
__global__ __launch_bounds__(256, 2) void gmfma32_k(
    const unsigned short* __restrict__ AH, const unsigned short* __restrict__ AM,
    const unsigned short* __restrict__ AL, float* __restrict__ outP,
    const unsigned short* __restrict__ WX, const int* __restrict__ nbr,
    const int* __restrict__ nactp, int Cin, int Cout, int Nmax, int cinCnt,
    int nocb) {
  __shared__ int s_nbr[9][128];
  __shared__ __align__(16) unsigned short s_a[3][2][128][8];
  __shared__ __align__(16) unsigned short s_w[3][2][128][8];
  const int n = nactp[0];
  const int gid = blockIdx.x;
  const int xcd = gid & 7, pos = gid >> 3;
  const int ocbI = pos % nocb;
  const int sb = (pos / nocb) * 8 + xcd;
  const int base = sb * 128;
  if (base >= n) return;
  const int ocb = ocbI * 128;
  const int t = threadIdx.x;
  for (int s = t; s < 1152; s += 256) {
    int i = s & 127, k = s >> 7;
    s_nbr[k][i] = (base + i < n) ? nbr[k * Nmax + base + i] : -1;
  }
  const int l = t & 63;
  const int wm = (t >> 6) & 1, wn = t >> 7;
  const int kh = l >> 5, lr = l & 31;
  const int skh = t >> 7, ssi = t & 127;   // staging slot: (khalf, site/oc)
  f32x16 acc[2][2];
#pragma unroll
  for (int a = 0; a < 2; ++a)
#pragma unroll
    for (int b = 0; b < 2; ++b)
#pragma unroll
      for (int r = 0; r < 16; ++r) acc[a][b][r] = 0.f;
  __syncthreads();
  const int cinStart = blockIdx.z * cinCnt;
  const int nck = cinCnt >> 4;
  const int np = 9 * nck;
  const size_t pstride = (size_t)9 * Cout * Cin;   // piece stride in wx
  const size_t kstrideW = (size_t)Cout * Cin;      // tap stride in wx
  const unsigned short* Wth = WX + ((size_t)(ocb + ssi)) * Cin + skh * 8;
  const float4 z4 = make_float4(0.f, 0.f, 0.f, 0.f);
  float4 pw0, pw1, pw2, pa0, pa1, pa2;
  // prologue: prefetch phase 0 (k=0, cc=0)
  {
    const unsigned short* W0 = Wth + cinStart;
    pw0 = *(const float4*)(W0);
    pw1 = *(const float4*)(W0 + pstride);
    pw2 = *(const float4*)(W0 + 2 * pstride);
    int row = s_nbr[0][ssi];
    if (row >= 0) {
      const size_t off = (size_t)row * Cin + cinStart + skh * 8;
      pa0 = *(const float4*)(AH + off);
      pa1 = *(const float4*)(AM + off);
      pa2 = *(const float4*)(AL + off);
    } else { pa0 = z4; pa1 = z4; pa2 = z4; }
  }
  int k = 0, cc = 0;
  for (int ph = 0; ph < np; ++ph) {
    __syncthreads();                       // prior phase frag reads complete
    *(float4*)&s_w[0][skh][ssi][0] = pw0;  // vmcnt wait for prefetch lands here
    *(float4*)&s_w[1][skh][ssi][0] = pw1;
    *(float4*)&s_w[2][skh][ssi][0] = pw2;
    *(float4*)&s_a[0][skh][ssi][0] = pa0;
    *(float4*)&s_a[1][skh][ssi][0] = pa1;
    *(float4*)&s_a[2][skh][ssi][0] = pa2;
    __syncthreads();                       // staging visible
    // issue next phase's staging loads (latency hides under MFMAs below)
    int cc2 = cc + 1, k2 = k;
    if (cc2 == nck) { cc2 = 0; ++k2; }
    if (ph + 1 < np) {
      const int c0n = cinStart + (cc2 << 4);
      const unsigned short* W0 = Wth + (size_t)k2 * kstrideW + c0n;
      pw0 = *(const float4*)(W0);
      pw1 = *(const float4*)(W0 + pstride);
      pw2 = *(const float4*)(W0 + 2 * pstride);
      int row = s_nbr[k2][ssi];
      if (row >= 0) {
        const size_t off = (size_t)row * Cin + c0n + skh * 8;
        pa0 = *(const float4*)(AH + off);
        pa1 = *(const float4*)(AM + off);
        pa2 = *(const float4*)(AL + off);
      } else { pa0 = z4; pa1 = z4; pa2 = z4; }
    }
    k = k2; cc = cc2;
    // frag reads + MFMA (current phase)
    bf8v af[2][3], wf[2][3];
#pragma unroll
    for (int mi = 0; mi < 2; ++mi)
#pragma unroll
      for (int p = 0; p < 3; ++p)
        af[mi][p] = *(const bf8v*)&s_a[p][kh][wm * 64 + mi * 32 + lr][0];
#pragma unroll
    for (int ni = 0; ni < 2; ++ni)
#pragma unroll
      for (int p = 0; p < 3; ++p)
        wf[ni][p] = *(const bf8v*)&s_w[p][kh][wn * 64 + ni * 32 + lr][0];
#pragma unroll
    for (int mi = 0; mi < 2; ++mi)
#pragma unroll
      for (int ni = 0; ni < 2; ++ni) {
        f32x16 c = acc[mi][ni];
        c = __builtin_amdgcn_mfma_f32_32x32x16_bf16(af[mi][0], wf[ni][0], c, 0, 0, 0);
        c = __builtin_amdgcn_mfma_f32_32x32x16_bf16(af[mi][0], wf[ni][1], c, 0, 0, 0);
        c = __builtin_amdgcn_mfma_f32_32x32x16_bf16(af[mi][1], wf[ni][0], c, 0, 0, 0);
        c = __builtin_amdgcn_mfma_f32_32x32x16_bf16(af[mi][1], wf[ni][1], c, 0, 0, 0);
        c = __builtin_amdgcn_mfma_f32_32x32x16_bf16(af[mi][0], wf[ni][2], c, 0, 0, 0);
        c = __builtin_amdgcn_mfma_f32_32x32x16_bf16(af[mi][2], wf[ni][0], c, 0, 0, 0);
        acc[mi][ni] = c;
      }
  }
  float* ob = outP + (size_t)blockIdx.z * Nmax * Cout;
#pragma unroll
  for (int mi = 0; mi < 2; ++mi) {
    const int sbase = base + wm * 64 + mi * 32 + 4 * kh;
#pragma unroll
    for (int ni = 0; ni < 2; ++ni) {
      const int oc = ocb + wn * 64 + ni * 32 + lr;
#pragma unroll
      for (int reg = 0; reg < 16; ++reg) {
        int gi = sbase + (reg & 3) + 8 * (reg >> 2);
        if (gi < n) ob[(size_t)gi * Cout + oc] = acc[mi][ni][reg];
      }
    }
  }
}

// ------------------------------------------------------------------ K-split combine (+bias+relu; optional f32 out; optional bf16x3 planes)
__global__ __launch_bounds__(256) void combine_k(const float* __restrict__ P,
    float* __restrict__ out, const float* __restrict__ bias,
    const int* __restrict__ nactp, int C, int S, int sliceStride,
    unsigned short* __restrict__ oh, unsigned short* __restrict__ om,
    unsigned short* __restrict__ ol) {
  int tg = blockIdx.x * 256 + threadIdx.x;
  int cg = C >> 2;
  int j = tg / cg, c4 = tg % cg;
  if (j >= nactp[0]) return;
  size_t o = (size_t)j * C + c4 * 4;
  float4 v = *(const float4*)(bias + c4 * 4);
  for (int s = 0; s < S; ++s) {
    float4 u = *(const float4*)(P + (size_t)s * sliceStride + o);
    v.x += u.x; v.y += u.y; v.z += u.z; v.w += u.w;
  }
  v.x = fmaxf(v.x, 0.f); v.y = fmaxf(v.y, 0.f);
  v.z = fmaxf(v.z, 0.f); v.w = fmaxf(v.w, 0.f);
  if (out) *(float4*)(out + o) = v;
  if (oh) {
    const float* pv = &v.x;
#pragma unroll
    for (int u = 0; u < 4; ++u) {
      float y = pv[u];
      unsigned short h = f2bf(y);
      float r1 = y - bf2f(h);
      unsigned short m2 = f2bf(r1);
      float r2 = r1 - bf2f(m2);
      oh[o + u] = h; om[o + u] = m2; ol[o + u] = f2bf(r2);
    }
  }
}

// ------------------------------------------------------------------ compact 2x2 maxpool (optional bf16x3 planes)
__global__ __launch_bounds__(256) void pool_c_k(const float* __restrict__ inF,
    float* __restrict__ outF, const int* __restrict__ listC,
    const int* __restrict__ imF, const int* __restrict__ nactp, int Hf, int C,
    unsigned short* __restrict__ oh, unsigned short* __restrict__ om,
    unsigned short* __restrict__ ol) {
  int tg = blockIdx.x * 256 + threadIdx.x;
  int cg = C >> 2;
  int j = tg / cg, c4 = tg % cg;
  if (j >= nactp[0]) return;
  int code = listC[j];
  int b = code >> 20, Y = (code >> 10) & 1023, X = code & 1023;
  float4 v = make_float4(0.f, 0.f, 0.f, 0.f);
#pragma unroll
  for (int dy = 0; dy < 2; ++dy)
#pragma unroll
    for (int dx = 0; dx < 2; ++dx) {
      int ci = imF[((size_t)b * Hf + 2 * Y + dy) * Hf + 2 * X + dx];
      if (ci >= 0) {
        float4 u = *(const float4*)(inF + (size_t)ci * C + c4 * 4);
        v.x = fmaxf(v.x, u.x); v.y = fmaxf(v.y, u.y);
        v.z = fmaxf(v.z, u.z); v.w = fmaxf(v.w, u.w);
      }
    }
  size_t o = (size_t)j * C + c4 * 4;
  *(float4*)(outF + o) = v;
  if (oh) {
    const float* pv = &v.x;
#pragma unroll
    for (int u = 0; u < 4; ++u) {
      float y = pv[u];
      unsigned short h = f2bf(y);
      float r1 = y - bf2f(h);
      unsigned short m2 = f2bf(r1);
      float r2 = r1 - bf2f(m2);
      oh[o + u] = h; om[o + u] = m2; ol[o + u] = f2bf(r2);
    }
  }
}

// ------------------------------------------------------------------ final pool -> dense [2,512,16,16]
__global__ __launch_bounds__(256) void pool_d_k(const float* __restrict__ inF,
    float* __restrict__ outD, const int* __restrict__ im32) {
  int tg = blockIdx.x * 256 + threadIdx.x;
  int c4 = tg & 127;
  int rest = tg >> 7;
  int X = rest & 15, Y = (rest >> 4) & 15, b = rest >> 8;
  float4 v = make_float4(0.f, 0.f, 0.f, 0.f);
#pragma unroll
  for (int dy = 0; dy < 2; ++dy)
#pragma unroll
    for (int dx = 0; dx < 2; ++dx) {
      int ci = im32[((size_t)b * 32 + 2 * Y + dy) * 32 + 2 * X + dx];
      if (ci >= 0) {
        float4 u = *(const float4*)(inF + (size_t)ci * 512 + c4 * 4);
        v.x = fmaxf(v.x, u.x); v.y = fmaxf(v.y, u.y);
        v.z = fmaxf(v.z, u.z); v.w = fmaxf(v.w, u.w);
      }
    }
  const float* pv = &v.x;
#pragma unroll
  for (int u = 0; u < 4; ++u) {
    int c = c4 * 4 + u;
    outD[(((size_t)b * 512 + c) * 16 + Y) * 16 + X] = pv[u];
  }
}

// ------------------------------------------------------------------ fully connected
template <bool RELU>
__global__ __launch_bounds__(256) void fc_k(const float* __restrict__ in,
                                            const float* __restrict__ w,
                                            const float* __restrict__ bias,
                                            float* __restrict__ out, int K,
                                            int R) {
  const int r = blockIdx.x;
  const int t = threadIdx.x;
  const float* wr = w + (size_t)r * K;
  float a0 = 0.f, a1 = 0.f;
  for (int k = t * 4; k < K; k += 1024) {
    float4 wv = *(const float4*)(wr + k);
    float4 x0 = *(const float4*)(in + k);
    float4 x1 = *(const float4*)(in + K + k);
    a0 += wv.x * x0.x + wv.y * x0.y + wv.z * x0.z + wv.w * x0.w;
    a1 += wv.x * x1.x + wv.y * x1.y + wv.z * x1.z + wv.w * x1.w;
  }
#pragma unroll
  for (int off = 32; off > 0; off >>= 1) {
    a0 += __shfl_down(a0, off);
    a1 += __shfl_down(a1, off);
  }
  __shared__ float s0[4], s1[4];
  const int lane = t & 63, wid = t >> 6;
  if (lane == 0) { s0[wid] = a0; s1[wid] = a1; }
  __syncthreads();
  if (t == 0) {
    float v0 = s0[0] + s0[1] + s0[2] + s0[3] + bias[r];
    float v1 = s1[0] + s1[1] + s1[2] + s1[3] + bias[r];
    if (RELU) { v0 = fmaxf(v0, 0.f); v1 = fmaxf(v1, 0.f); }
    out[r] = v0;
    out[R + r] = v1;
  }
}

// ------------------------------------------------------------------ launch
extern "C" void kernel_launch(void* const* d_in, const int* in_sizes, int n_in,
                              void* d_out, int out_size, void* d_ws,
                              size_t ws_size, hipStream_t stream) {
  (void)in_sizes; (void)n_in; (void)out_size; (void)ws_size;
  const float* x = (const float*)d_in[0];
  const float* Wc[14];
  const float* Bc[14];
  for (int i = 1; i <= 13; ++i) {
    Wc[i] = (const float*)d_in[2 * i - 1];
    Bc[i] = (const float*)d_in[2 * i];
  }
  const float* fw1 = (const float*)d_in[27];
  const float* fb1 = (const float*)d_in[28];
  const float* fw2 = (const float*)d_in[29];
  const float* fb2 = (const float*)d_in[30];
  const float* fw3 = (const float*)d_in[31];
  const float* fb3 = (const float*)d_in[32];
  const float* fw4 = (const float*)d_in[33];
  const float* fb4 = (const float*)d_in[34];

  static const int CH[14] = {1, 64, 64, 128, 128, 256, 256, 256,
                             512, 512, 512, 512, 512, 512};

  char* ws = (char*)d_ws;
  size_t cur = 0;
  auto alloc = [&](size_t bytes) {
    size_t o = cur;
    cur += (bytes + 255) & ~(size_t)255;
    return o;
  };
  // fp32 weight transposes (L1-L4)
  size_t wtOff[5];
  for (int i = 1; i <= 4; ++i)
    wtOff[i] = alloc((size_t)CH[i] * CH[i - 1] * 9 * 4);
  float* wT[5];
  for (int i = 1; i <= 4; ++i) wT[i] = (float*)(ws + wtOff[i]);
  // bf16x3 weight planes (L5-L13): layout [p][k][oc][cin]
  unsigned short* wX[14];
  for (int i = 5; i <= 13; ++i)
    wX[i] = (unsigned short*)(ws + alloc((size_t)3 * 9 * CH[i] * CH[i - 1] * 2));
  // features. Praw (K-split partials, contiguous from A1) may extend through
  // A5 (dead after L7 pool): L5-7 need 42MB (< A1..P4 63.9MB), L8-10 z=4 need
  // 67.1MB (< A1..A5 84.9MB), L11-13 33.6MB.
  float* F0  = (float*)(ws + alloc((size_t)NMAX512 * 1 * 4));
  size_t a1Off = alloc((size_t)NMAX512 * 64 * 4);
  float* A1  = (float*)(ws + a1Off);
  float* Praw = A1;
  float* A2  = (float*)(ws + alloc((size_t)NMAX512 * 64 * 4));
  float* P2  = (float*)(ws + alloc((size_t)NMAX256 * 64 * 4));
  float* A3  = (float*)(ws + alloc((size_t)NMAX256 * 128 * 4));
  float* A4  = (float*)(ws + alloc((size_t)NMAX256 * 128 * 4));
  float* P4  = (float*)(ws + alloc((size_t)NMAX128 * 128 * 4));
  float* A5  = (float*)(ws + alloc((size_t)NMAX128 * 256 * 4));
  float* P7  = (float*)(ws + alloc((size_t)NMAX64 * 256 * 4));
  float* A8  = (float*)(ws + alloc((size_t)NMAX64 * 512 * 4));
  float* P10 = (float*)(ws + alloc((size_t)NMAX32 * 512 * 4));
  float* A11 = (float*)(ws + alloc((size_t)NMAX32 * 512 * 4));
  float* D13 = (float*)(ws + alloc((size_t)NB * 512 * 16 * 16 * 4));
  float* F1  = (float*)(ws + alloc(NB * 1024 * 4));
  float* F2  = (float*)(ws + alloc(NB * 512 * 4));
  float* F3  = (float*)(ws + alloc(NB * 256 * 4));
  // bf16x3 feature plane arenas (ping-pong X/Y)
  const size_t PLE = (size_t)NMAX128 * 256;
  unsigned short* XH = (unsigned short*)(ws + alloc(PLE * 2));
  unsigned short* XM = (unsigned short*)(ws + alloc(PLE * 2));
  unsigned short* XL = (unsigned short*)(ws + alloc(PLE * 2));
  unsigned short* YH = (unsigned short*)(ws + alloc(PLE * 2));
  unsigned short* YM = (unsigned short*)(ws + alloc(PLE * 2));
  unsigned short* YL = (unsigned short*)(ws + alloc(PLE * 2));
  // index maps / lists / neighbor tables / counters
  int* im512 = (int*)(ws + alloc((size_t)NB * 512 * 512 * 4));
  int* im256 = (int*)(ws + alloc((size_t)NB * 256 * 256 * 4));
  int* im128 = (int*)(ws + alloc((size_t)NB * 128 * 128 * 4));
  int* im64  = (int*)(ws + alloc((size_t)NB * 64 * 64 * 4));
  int* im32  = (int*)(ws + alloc((size_t)NB * 32 * 32 * 4));
  int* l512 = (int*)(ws + alloc((size_t)NMAX512 * 4));
  int* l256 = (int*)(ws + alloc((size_t)NMAX256 * 4));
  int* l128 = (int*)(ws + alloc((size_t)NMAX128 * 4));
  int* l64  = (int*)(ws + alloc((size_t)NMAX64 * 4));
  int* l32  = (int*)(ws + alloc((size_t)NMAX32 * 4));
  int* nb512 = (int*)(ws + alloc((size_t)9 * NMAX512 * 4));
  int* nb256 = (int*)(ws + alloc((size_t)9 * NMAX256 * 4));
  int* nb128 = (int*)(ws + alloc((size_t)9 * NMAX128 * 4));
  int* nb64  = (int*)(ws + alloc((size_t)9 * NMAX64 * 4));
  int* nb32  = (int*)(ws + alloc((size_t)9 * NMAX32 * 4));
  int* nact = (int*)(ws + alloc(256));

  const dim3 blk(256);
  hipMemsetAsync(nact, 0, 32, stream);

  // ---- lists / index maps / neighbors
  hipLaunchKernelGGL(build_l0_k, dim3(2048), blk, 0, stream, x, l512, im512, F0, nact + 0, NB * 512 * 512, NMAX512);
  hipLaunchKernelGGL(build_pl_k, dim3(512), blk, 0, stream, im512, l256, im256, nact + 1, 256, NMAX256);
  hipLaunchKernelGGL(build_pl_k, dim3(128), blk, 0, stream, im256, l128, im128, nact + 2, 128, NMAX128);
  hipLaunchKernelGGL(build_pl_k, dim3(32), blk, 0, stream, im128, l64, im64, nact + 3, 64, NMAX64);
  hipLaunchKernelGGL(build_pl_k, dim3(8), blk, 0, stream, im64, l32, im32, nact + 4, 32, NMAX32);
  hipLaunchKernelGGL(build_nbr_k, dim3(NMAX512 / 256), blk, 0, stream, l512, im512, nact + 0, nb512, 512, NMAX512);
  hipLaunchKernelGGL(build_nbr_k, dim3(NMAX256 / 256), blk, 0, stream, l256, im256, nact + 1, nb256, 256, NMAX256);
  hipLaunchKernelGGL(build_nbr_k, dim3(NMAX128 / 256), blk, 0, stream, l128, im128, nact + 2, nb128, 128, NMAX128);
  hipLaunchKernelGGL(build_nbr_k, dim3(NMAX64 / 256), blk, 0, stream, l64, im64, nact + 3, nb64, 64, NMAX64);
  hipLaunchKernelGGL(build_nbr_k, dim3(NMAX32 / 256), blk, 0, stream, l32, im32, nact + 4, nb32, 32, NMAX32);

  // ---- weight prep
  for (int i = 1; i <= 4; ++i) {
    int R = CH[i], C = CH[i - 1] * 9;
    hipLaunchKernelGGL(transpose_k, dim3((C + 31) / 32, (R + 31) / 32), blk, 0,
                       stream, Wc[i], wT[i], R, C);
  }
  for (int i = 5; i <= 13; ++i) {
    int e = CH[i] * CH[i - 1];
    hipLaunchKernelGGL(wprep_k, dim3((e + 255) / 256), blk, 0, stream, Wc[i],
                       wX[i], CH[i], CH[i - 1]);
  }

  // ---- L1-L4 (fp32 path)
  hipLaunchKernelGGL((gconv_k<1, 64, 64, 4, 4>), dim3(512, 1, 1), blk, 0, stream,
                     F0, A1, wT[1], Bc[1], nb512, nact + 0, 1, 64, NMAX512, 1, 1);
  hipLaunchKernelGGL((gconv_k<8, 64, 64, 4, 4>), dim3(512, 1, 1), blk, 0, stream,
                     A1, A2, wT[2], Bc[2], nb512, nact + 0, 64, 64, NMAX512, 64, 1);
  hipLaunchKernelGGL(pool_c_k, dim3(NMAX256 * 16 / 256), blk, 0, stream, A2, P2,
                     l256, im512, nact + 1, 512, 64, (unsigned short*)nullptr,
                     (unsigned short*)nullptr, (unsigned short*)nullptr);
  hipLaunchKernelGGL((gconv_k<8, 64, 128, 4, 8>), dim3(448, 1, 1), blk, 0, stream,
                     P2, A3, wT[3], Bc[3], nb256, nact + 1, 64, 128, NMAX256, 64, 1);
  hipLaunchKernelGGL((gconv_k<8, 64, 128, 4, 8>), dim3(448, 1, 1), blk, 0, stream,
                     A3, A4, wT[4], Bc[4], nb256, nact + 1, 128, 128, NMAX256, 128, 1);
  hipLaunchKernelGGL(pool_c_k, dim3(NMAX128 * 32 / 256), blk, 0, stream, A4, P4,
                     l128, im256, nact + 2, 256, 128, XH, XM, XL);

  // ---- L5-L13 (bf16x3 32x32 MFMA + T14 prefetch, RAW K-split -> Praw + combine)
  unsigned short* NUL = nullptr;
  const int SL128 = NMAX128 * 256;
  const int SL64  = NMAX64 * 512;
  const int SL32  = NMAX32 * 512;
  // L5: 128->256 @128, z=2 (cinCnt 64)
  hipLaunchKernelGGL(gmfma32_k, dim3(320, 1, 2), blk, 0, stream,
                     XH, XM, XL, Praw, wX[5], nb128, nact + 2, 128, 256, NMAX128, 64, 2);
  hipLaunchKernelGGL(combine_k, dim3(NMAX128 * 64 / 256), blk, 0, stream, Praw,
                     (float*)nullptr, Bc[5], nact + 2, 256, 2, SL128, YH, YM, YL);
  // L6: 256->256 @128, z=2 (cinCnt 128)
  hipLaunchKernelGGL(gmfma32_k, dim3(320, 1, 2), blk, 0, stream,
                     YH, YM, YL, Praw, wX[6], nb128, nact + 2, 256, 256, NMAX128, 128, 2);
  hipLaunchKernelGGL(combine_k, dim3(NMAX128 * 64 / 256), blk, 0, stream, Praw,
                     (float*)nullptr, Bc[6], nact + 2, 256, 2, SL128, XH, XM, XL);
  // L7: 256->256 @128, z=2 -> f32 only (feeds pool)
  hipLaunchKernelGGL(gmfma32_k, dim3(320, 1, 2), blk, 0, stream,
                     XH, XM, XL, Praw, wX[7], nb128, nact + 2, 256, 256, NMAX128, 128, 2);
  hipLaunchKernelGGL(combine_k, dim3(NMAX128 * 64 / 256), blk, 0, stream, Praw,
                     A5, Bc[7], nact + 2, 256, 2, SL128, NUL, NUL, NUL);
  hipLaunchKernelGGL(pool_c_k, dim3(NMAX64 * 64 / 256), blk, 0, stream, A5, P7,
                     l64, im128, nact + 3, 128, 256, XH, XM, XL);
  // L8: 256->512 @64, z=4 (cinCnt 64); grid 256 x z4 = 1024 instances
  hipLaunchKernelGGL(gmfma32_k, dim3(256, 1, 4), blk, 0, stream,
                     XH, XM, XL, Praw, wX[8], nb64, nact + 3, 256, 512, NMAX64, 64, 4);
  hipLaunchKernelGGL(combine_k, dim3(NMAX64 * 128 / 256), blk, 0, stream, Praw,
                     (float*)nullptr, Bc[8], nact + 3, 512, 4, SL64, YH, YM, YL);
  // L9: 512->512 @64, z=4 (cinCnt 128)
  hipLaunchKernelGGL(gmfma32_k, dim3(256, 1, 4), blk, 0, stream,
                     YH, YM, YL, Praw, wX[9], nb64, nact + 3, 512, 512, NMAX64, 128, 4);
  hipLaunchKernelGGL(combine_k, dim3(NMAX64 * 128 / 256), blk, 0, stream, Praw,
                     (float*)nullptr, Bc[9], nact + 3, 512, 4, SL64, XH, XM, XL);
  // L10: 512->512 @64, z=4 -> f32 only (feeds pool)
  hipLaunchKernelGGL(gmfma32_k, dim3(256, 1, 4), blk, 0, stream,
                     XH, XM, XL, Praw, wX[10], nb64, nact + 3, 512, 512, NMAX64, 128, 4);
  hipLaunchKernelGGL(combine_k, dim3(NMAX64 * 128 / 256), blk, 0, stream, Praw,
                     A8, Bc[10], nact + 3, 512, 4, SL64, NUL, NUL, NUL);
  hipLaunchKernelGGL(pool_c_k, dim3(NMAX32 * 128 / 256), blk, 0, stream, A8, P10,
                     l32, im64, nact + 4, 64, 512, XH, XM, XL);
  // L11-13: 512->512 @32, z=8 (cinCnt 64)
  hipLaunchKernelGGL(gmfma32_k, dim3(64, 1, 8), blk, 0, stream,
                     XH, XM, XL, Praw, wX[11], nb32, nact + 4, 512, 512, NMAX32, 64, 4);
  hipLaunchKernelGGL(combine_k, dim3(NMAX32 * 128 / 256), blk, 0, stream, Praw,
                     (float*)nullptr, Bc[11], nact + 4, 512, 8, SL32, YH, YM, YL);
  hipLaunchKernelGGL(gmfma32_k, dim3(64, 1, 8), blk, 0, stream,
                     YH, YM, YL, Praw, wX[12], nb32, nact + 4, 512, 512, NMAX32, 64, 4);
  hipLaunchKernelGGL(combine_k, dim3(NMAX32 * 128 / 256), blk, 0, stream, Praw,
                     (float*)nullptr, Bc[12], nact + 4, 512, 8, SL32, XH, XM, XL);
  hipLaunchKernelGGL(gmfma32_k, dim3(64, 1, 8), blk, 0, stream,
                     XH, XM, XL, Praw, wX[13], nb32, nact + 4, 512, 512, NMAX32, 64, 4);
  hipLaunchKernelGGL(combine_k, dim3(NMAX32 * 128 / 256), blk, 0, stream, Praw,
                     A11, Bc[13], nact + 4, 512, 8, SL32, NUL, NUL, NUL);
  hipLaunchKernelGGL(pool_d_k, dim3(256), blk, 0, stream, A11, D13, im32);

  // ---- MLP
  hipLaunchKernelGGL((fc_k<true>), dim3(1024), blk, 0, stream, D13, fw1, fb1, F1, 131072, 1024);
  hipLaunchKernelGGL((fc_k<true>), dim3(512), blk, 0, stream, F1, fw2, fb2, F2, 1024, 512);
  hipLaunchKernelGGL((fc_k<true>), dim3(256), blk, 0, stream, F2, fw3, fb3, F3, 512, 256);
  hipLaunchKernelGGL((fc_k<false>), dim3(2), blk, 0, stream, F3, fw4, fb4, (float*)d_out, 256, 2);
}